// Round 7
// baseline (330.675 us; speedup 1.0000x reference)
//
#include <hip/hip_runtime.h>

#define L_ 2048
#define B_ 2
#define E_ 1024
#define H_ 16
#define HD_ 64
#define M_ 4096   // L_*B_
#define K_ 1024   // E_

typedef unsigned short u16;
typedef unsigned int u32;
using short8  = __attribute__((ext_vector_type(8))) short;
using short4v = __attribute__((ext_vector_type(4))) short;
using floatx4 = __attribute__((ext_vector_type(4))) float;

__device__ inline u16 f2b(float f) {            // fp32 -> bf16 RNE
  unsigned u = __float_as_uint(f);
  u += 0x7FFF + ((u >> 16) & 1);
  return (u16)(u >> 16);
}

// two fp32 -> packed bf16 pair, round-half-up
__device__ inline u32 pack2(float a, float b) {
  u32 ua = __float_as_uint(a) + 0x8000u;
  u32 ub = __float_as_uint(b) + 0x8000u;
  return (ua >> 16) | (ub & 0xFFFF0000u);
}

__device__ inline floatx4 mfma16(short8 a, short8 b, floatx4 c) {
  return __builtin_amdgcn_mfma_f32_16x16x32_bf16(a, b, c, 0, 0, 0);
}

// async global->LDS, 16B per lane; lds dest is wave-uniform base + lane*16
__device__ inline void gload16(const void* g, void* l) {
  __builtin_amdgcn_global_load_lds(
      (const __attribute__((address_space(1))) u32*)g,
      (__attribute__((address_space(3))) u32*)l, 16, 0, 0);
}

// ---------------- fp32 -> bf16 conversion (all 5 tensors, one launch) ------
__global__ void convall(const float* __restrict__ q, const float* __restrict__ k,
                        const float* __restrict__ v, const float* __restrict__ wi,
                        const float* __restrict__ wo,
                        u16* __restrict__ xb, u16* __restrict__ wib,
                        u16* __restrict__ wob) {
  const int z = blockIdx.z;
  const float* src;
  u16* dst;
  int n4;
  if (z < 3)      { src = (z == 0 ? q : (z == 1 ? k : v));
                    dst = xb + (size_t)z * M_ * K_; n4 = M_ * K_ / 4; }
  else if (z == 3){ src = wi; dst = wib; n4 = 3 * E_ * K_ / 4; }
  else            { src = wo; dst = wob; n4 = E_ * K_ / 4; }
  int i = blockIdx.x * blockDim.x + threadIdx.x;
  if (i < n4) {
    float4 val = ((const float4*)src)[i];
    ushort4 o;
    o.x = f2b(val.x); o.y = f2b(val.y); o.z = f2b(val.z); o.w = f2b(val.w);
    ((ushort4*)dst)[i] = o;
  }
}

// ---------------- bf16 GEMM (QKV projection): C = A * W^T + bias ----------------
// V is stored column-permuted within 32-col groups so attn1's PV A-frag is a
// single natural b128 read: pos(l) = ((l>>2)&3)*8 + ((l>>4)&1)*4 + (l&3).
// Double-buffered LDS staging, ONE barrier per K-step.
__global__ __launch_bounds__(256) void gemm_qkv(
    const u16* __restrict__ A, const u16* __restrict__ W, const float* __restrict__ bias,
    u16* __restrict__ qh, u16* __restrict__ kh, u16* __restrict__ vhT)
{
  __shared__ __align__(16) u16 As[2][128 * 32];
  __shared__ __align__(16) u16 Bs[2][128 * 32];
  const int p = blockIdx.z;
  const u16* Ap = A + (size_t)p * M_ * K_;
  const u16* Wp = W + (size_t)p * E_ * K_;
  const float* bp = bias + p * E_;
  const int row0 = blockIdx.y * 128, col0 = blockIdx.x * 128;
  const int t = threadIdx.x, lane = t & 63, wv = t >> 6;
  const int lanem = lane & 15, quad = lane >> 4;
  const int wm = wv >> 1, wn = wv & 1;

  int f0 = t, f1 = 256 + t;
  int r0s = f0 >> 2, q0s = (f0 & 3) ^ ((r0s >> 1) & 3);
  int r1s = f1 >> 2, q1s = (f1 & 3) ^ ((r1s >> 1) & 3);

  floatx4 acc[4][4];
#pragma unroll
  for (int mi = 0; mi < 4; ++mi)
#pragma unroll
    for (int ni = 0; ni < 4; ++ni) acc[mi][ni] = (floatx4){0.f, 0.f, 0.f, 0.f};

  const int swz = (lanem >> 1) & 3;

  auto STAGE = [&](int buf, int k0) {
    gload16(Ap + (size_t)(row0 + r0s) * K_ + k0 + q0s * 8, (char*)As[buf] + wv * 1024);
    gload16(Wp + (size_t)(col0 + r0s) * K_ + k0 + q0s * 8, (char*)Bs[buf] + wv * 1024);
    gload16(Ap + (size_t)(row0 + r1s) * K_ + k0 + q1s * 8, (char*)As[buf] + 4096 + wv * 1024);
    gload16(Wp + (size_t)(col0 + r1s) * K_ + k0 + q1s * 8, (char*)Bs[buf] + 4096 + wv * 1024);
  };

  STAGE(0, 0);                               // preload tile 0
  for (int k0 = 0; k0 < K_; k0 += 32) {
    const int buf = (k0 >> 5) & 1;
    __syncthreads();                         // drains tile k0's loads; other buf free
    if (k0 + 32 < K_) STAGE(buf ^ 1, k0 + 32);
    short8 af[4], bfg[4];
#pragma unroll
    for (int mi = 0; mi < 4; ++mi) {
      int r = wm * 64 + mi * 16 + lanem;
      af[mi] = *(const short8*)((const char*)As[buf] + r * 64 + (quad ^ swz) * 16);
    }
#pragma unroll
    for (int ni = 0; ni < 4; ++ni) {
      int r = wn * 64 + ni * 16 + lanem;
      bfg[ni] = *(const short8*)((const char*)Bs[buf] + r * 64 + (quad ^ swz) * 16);
    }
#pragma unroll
    for (int mi = 0; mi < 4; ++mi)
#pragma unroll
      for (int ni = 0; ni < 4; ++ni)
        acc[mi][ni] = mfma16(af[mi], bfg[ni], acc[mi][ni]);
  }

#pragma unroll
  for (int ni = 0; ni < 4; ++ni) {
    int gc = col0 + wn * 64 + ni * 16 + lanem;
    float bv = bp[gc];
#pragma unroll
    for (int mi = 0; mi < 4; ++mi) {
      int gr0 = row0 + wm * 64 + mi * 16 + quad * 4;
#pragma unroll
      for (int v = 0; v < 4; ++v) {
        float val = acc[mi][ni][v] + bv;
        int r = gr0 + v;
        int l = r >> 1, bb = r & 1, hh = gc >> 6, d = gc & 63;
        u16 x = f2b(val);
        if (p == 0)      qh[(((size_t)bb * H_ + hh) * L_ + l) * HD_ + d] = x;
        else if (p == 1) kh[(((size_t)bb * H_ + hh) * L_ + l) * HD_ + d] = x;
        else {
          int lp = (l & ~31) | (((l >> 2) & 3) * 8 + ((l >> 4) & 1) * 4 + (l & 3));
          vhT[(((size_t)bb * H_ + hh) * HD_ + d) * L_ + lp] = x;
        }
      }
    }
  }
}

// ---------------- flash attention: folded-triangle blocks, dbuf staging ----------------
__global__ __launch_bounds__(256, 2) void attn1(
    const u16* __restrict__ qh, const u16* __restrict__ kh, const u16* __restrict__ vhT,
    u16* __restrict__ ctx, float* __restrict__ li_ws)
{
  __shared__ __align__(16) u16 Ks[2][64 * 64];
  __shared__ __align__(16) u16 Vs[2][64 * 64];
  const int g = blockIdx.x;                    // 0..15
  const int h = blockIdx.y, b = blockIdx.z;
  const int t = threadIdx.x, lane = t & 63, wv = t >> 6;
  const int lanem = lane & 15, quad = lane >> 4;
  const int bh = b * H_ + h;
  const int gB = (L_ / 64 - 1) - g;            // 31-g
  const int rowA = g * 64 + wv * 16 + lanem;
  const int rowB = gB * 64 + wv * 16 + lanem;

  const u16* qpA = qh + ((size_t)bh * L_ + rowA) * HD_;
  const u16* qpB = qh + ((size_t)bh * L_ + rowB) * HD_;
  short8 qA0 = *(const short8*)(qpA + quad * 8);
  short8 qA1 = *(const short8*)(qpA + 32 + quad * 8);
  short8 qB0 = *(const short8*)(qpB + quad * 8);
  short8 qB1 = *(const short8*)(qpB + 32 + quad * 8);

  const int srow = lane >> 3;
  const int spiece = (lane & 7) ^ srow;
  const u16* ksrc = kh + ((size_t)bh * L_ + wv * 16 + srow) * HD_ + spiece * 8;
  const u16* vsrc = vhT + ((size_t)bh * HD_ + wv * 16 + srow) * L_ + spiece * 8;

  const int ntiles = 32 - g;
  auto stage = [&](int buf) {
    gload16(ksrc, (char*)Ks[buf] + wv * 2048);
    gload16(ksrc + 8 * HD_, (char*)Ks[buf] + wv * 2048 + 1024);
    gload16(vsrc, (char*)Vs[buf] + wv * 2048);
    gload16(vsrc + (size_t)8 * L_, (char*)Vs[buf] + wv * 2048 + 1024);
    ksrc += 64 * HD_;
    vsrc += 64;
  };

  const int swz = lanem & 7;
  const int cb0 = lanem * 128 + ((quad ^ swz)) * 16;
  const int cb1 = lanem * 128 + ((quad ^ swz) ^ 4) * 16;

  float liA = 0.f, liB = 0.f;
  floatx4 oA[4], oB[4];
#pragma unroll
  for (int d = 0; d < 4; ++d) { oA[d] = (floatx4){0.f,0.f,0.f,0.f}; oB[d] = oA[d]; }

  int j0 = 0, tcur = 0;

  auto do_tile = [&](int modeA, int modeB) {
    __syncthreads();                      // drains tile tcur's loads; prev buf free
    if (tcur + 1 < ntiles) stage((tcur + 1) & 1);
    const char* kbuf = (const char*)Ks[tcur & 1];
    const char* vbuf = (const char*)Vs[tcur & 1];

    floatx4 sA[4], sB[4];
#pragma unroll
    for (int jf = 0; jf < 4; ++jf) {
      short8 a0 = *(const short8*)(kbuf + cb0 + jf * 2048);
      short8 a1 = *(const short8*)(kbuf + cb1 + jf * 2048);
      floatx4 z = (floatx4){0.f,0.f,0.f,0.f};
      if (modeA != 2) sA[jf] = mfma16(a1, qA1, mfma16(a0, qA0, z));
      sB[jf] = mfma16(a1, qB1, mfma16(a0, qB0, z));
    }

    short8 pbA[2], pbB[2];
    auto soft = [&](floatx4* st, int row, float& li, short8* pb, int masked) {
#pragma unroll
      for (int jc = 0; jc < 2; ++jc) {
        float p[8];
#pragma unroll
        for (int r = 0; r < 4; ++r) {
          int ja = j0 + jc * 32 + quad * 4 + r;
          float e0 = __expf(st[jc * 2][r] * 0.125f);
          float e1 = __expf(st[jc * 2 + 1][r] * 0.125f);
          if (masked) {
            e0 = (ja <= row) ? e0 : 0.f;
            e1 = (ja + 16 <= row) ? e1 : 0.f;
          }
          li += e0 + e1;
          p[r] = e0; p[4 + r] = e1;
        }
        union { u32 w[4]; short8 s; } u;
        u.w[0] = pack2(p[0], p[1]); u.w[1] = pack2(p[2], p[3]);
        u.w[2] = pack2(p[4], p[5]); u.w[3] = pack2(p[6], p[7]);
        pb[jc] = u.s;
      }
    };
    if (modeA == 0) soft(sA, rowA, liA, pbA, 0);
    else if (modeA == 1) soft(sA, rowA, liA, pbA, 1);
    if (modeB == 0) soft(sB, rowB, liB, pbB, 0);
    else soft(sB, rowB, liB, pbB, 1);

#pragma unroll
    for (int jc = 0; jc < 2; ++jc) {
      const int base = (jc == 0) ? cb0 : cb1;
#pragma unroll
      for (int dbl = 0; dbl < 4; ++dbl) {
        short8 vf = *(const short8*)(vbuf + base + dbl * 2048);
        if (modeA != 2) oA[dbl] = mfma16(vf, pbA[jc], oA[dbl]);
        oB[dbl] = mfma16(vf, pbB[jc], oB[dbl]);
      }
    }
    j0 += 64;
    ++tcur;
  };

  stage(0);                                   // preload tile 0
  for (int jt = 0; jt < g; ++jt) do_tile(0, 0);   // both groups, unmasked
  do_tile(1, 0);                                  // A diagonal, B unmasked
  for (int jt = g + 1; jt <= 30 - g; ++jt) do_tile(2, 0);  // B only
  do_tile(2, 1);                                  // B diagonal

  liA += __shfl_xor(liA, 16); liA += __shfl_xor(liA, 32);
  liB += __shfl_xor(liB, 16); liB += __shfl_xor(liB, 32);
  float invA = 1.0f / liA, invB = 1.0f / liB;

  u16* cA = ctx + ((size_t)rowA * B_ + b) * E_ + h * HD_ + quad * 4;
  u16* cB = ctx + ((size_t)rowB * B_ + b) * E_ + h * HD_ + quad * 4;
#pragma unroll
  for (int dbl = 0; dbl < 4; ++dbl) {
    ushort4 pkA, pkB;
    pkA.x = f2b(oA[dbl][0] * invA); pkA.y = f2b(oA[dbl][1] * invA);
    pkA.z = f2b(oA[dbl][2] * invA); pkA.w = f2b(oA[dbl][3] * invA);
    pkB.x = f2b(oB[dbl][0] * invB); pkB.y = f2b(oB[dbl][1] * invB);
    pkB.z = f2b(oB[dbl][2] * invB); pkB.w = f2b(oB[dbl][3] * invB);
    *(ushort4*)(cA + dbl * 16) = pkA;
    *(ushort4*)(cB + dbl * 16) = pkB;
  }
  if (quad == 0) {
    li_ws[(size_t)bh * L_ + rowA] = invA;
    li_ws[(size_t)bh * L_ + rowB] = invB;
  }
}

// ---------------- fused tail: attn2 (z<2) + out-projection gemm (z==2) ----------------
// attn2 is latency-bound (all pipes <25% busy, occupancy 16%); the out-proj
// gemm is MFMA-heavy and independent (ctx/w_out vs qh/kh/li_ws; disjoint
// d_out halves). Grid-fused so gemm blocks co-schedule into attn2's idle
// issue slots. Both roles need exactly 32 KB LDS -> one shared buffer.
__global__ __launch_bounds__(256) void fused_tail(
    const u16* __restrict__ qh, const u16* __restrict__ kh,
    const float* __restrict__ li_ws, float* __restrict__ out2,
    const u16* __restrict__ ctx, const u16* __restrict__ wo,
    const float* __restrict__ bo, float* __restrict__ outp)
{
  __shared__ __align__(16) u16 smem[4][64 * 64];   // 32 KB, shared by both roles
  const int t = threadIdx.x, lane = t & 63, wv = t >> 6;
  const int lanem = lane & 15, quad = lane >> 4;

  if (blockIdx.z == 2) {
    // ---------------- out-projection gemm: outp = ctx * wo^T + bo ----------------
    if (blockIdx.x >= 8) return;
    u16* base = &smem[0][0];
    const int row0 = blockIdx.y * 128, col0 = blockIdx.x * 128;
    const int wm = wv >> 1, wn = wv & 1;

    int f0 = t, f1 = 256 + t;
    int r0s = f0 >> 2, q0s = (f0 & 3) ^ ((r0s >> 1) & 3);
    int r1s = f1 >> 2, q1s = (f1 & 3) ^ ((r1s >> 1) & 3);

    floatx4 acc[4][4];
#pragma unroll
    for (int mi = 0; mi < 4; ++mi)
#pragma unroll
      for (int ni = 0; ni < 4; ++ni) acc[mi][ni] = (floatx4){0.f, 0.f, 0.f, 0.f};

    const int swz = (lanem >> 1) & 3;

    auto STAGE = [&](int buf, int k0) {
      u16* As = base + buf * 4096;          // 8 KB each
      u16* Bs = base + 8192 + buf * 4096;
      gload16(ctx + (size_t)(row0 + r0s) * K_ + k0 + q0s * 8, (char*)As + wv * 1024);
      gload16(wo  + (size_t)(col0 + r0s) * K_ + k0 + q0s * 8, (char*)Bs + wv * 1024);
      gload16(ctx + (size_t)(row0 + r1s) * K_ + k0 + q1s * 8, (char*)As + 4096 + wv * 1024);
      gload16(wo  + (size_t)(col0 + r1s) * K_ + k0 + q1s * 8, (char*)Bs + 4096 + wv * 1024);
    };

    STAGE(0, 0);
    for (int k0 = 0; k0 < K_; k0 += 32) {
      const int buf = (k0 >> 5) & 1;
      __syncthreads();
      if (k0 + 32 < K_) STAGE(buf ^ 1, k0 + 32);
      const u16* As = base + buf * 4096;
      const u16* Bs = base + 8192 + buf * 4096;
      short8 af[4], bfg[4];
#pragma unroll
      for (int mi = 0; mi < 4; ++mi) {
        int r = wm * 64 + mi * 16 + lanem;
        af[mi] = *(const short8*)((const char*)As + r * 64 + (quad ^ swz) * 16);
      }
#pragma unroll
      for (int ni = 0; ni < 4; ++ni) {
        int r = wn * 64 + ni * 16 + lanem;
        bfg[ni] = *(const short8*)((const char*)Bs + r * 64 + (quad ^ swz) * 16);
      }
#pragma unroll
      for (int mi = 0; mi < 4; ++mi)
#pragma unroll
        for (int ni = 0; ni < 4; ++ni)
          acc[mi][ni] = mfma16(af[mi], bfg[ni], acc[mi][ni]);
    }

#pragma unroll
    for (int ni = 0; ni < 4; ++ni) {
      int gc = col0 + wn * 64 + ni * 16 + lanem;
      float bv = bo[gc];
#pragma unroll
      for (int mi = 0; mi < 4; ++mi) {
        int gr0 = row0 + wm * 64 + mi * 16 + quad * 4;
#pragma unroll
        for (int v = 0; v < 4; ++v)
          outp[(size_t)(gr0 + v) * E_ + gc] = acc[mi][ni][v] + bv;
      }
    }
    return;
  }

  // ---------------- attn2: head-averaged attention probs ----------------
  const int jt = blockIdx.x, it = blockIdx.y, b = blockIdx.z;
  const int i0 = it * 64 + wv * 16;
  const int j0 = jt * 64;
  float* ob = out2 + (size_t)b * L_ * L_;

  if (jt > it) {          // strictly upper block: zeros (d_out is poisoned)
    float4 z = {0.f, 0.f, 0.f, 0.f};
    float* rp = ob + (size_t)(i0 + lanem) * L_ + j0 + quad * 16;
    ((float4*)rp)[0] = z; ((float4*)rp)[1] = z;
    ((float4*)rp)[2] = z; ((float4*)rp)[3] = z;
    return;
  }

  const int srow = lane >> 3;
  const int spiece = (lane & 7) ^ srow;
  const int swz = lanem & 7;

  auto stage = [&](int p, int buf) {
#pragma unroll
    for (int hh = 0; hh < 2; ++hh) {
      const u16* kg = kh + ((size_t)(b * H_ + 2 * p + hh) * L_ + j0) * HD_;
#pragma unroll
      for (int k = wv * 2; k < wv * 2 + 2; ++k)
        gload16(kg + (size_t)(k * 8 + srow) * HD_ + spiece * 8,
                (char*)smem[buf * 2 + hh] + k * 1024);
    }
  };
  auto loadQ = [&](int p, short8 q[2][2], floatx4 lf[2]) {
#pragma unroll
    for (int hh = 0; hh < 2; ++hh) {
      int bh = b * H_ + 2 * p + hh;
      const u16* qb = qh + ((size_t)bh * L_ + i0 + lanem) * HD_;
      q[hh][0] = *(const short8*)(qb + quad * 8);
      q[hh][1] = *(const short8*)(qb + 32 + quad * 8);
      lf[hh] = *(const floatx4*)(li_ws + (size_t)bh * L_ + i0 + quad * 4);
    }
  };

  float acc[4][4] = {};   // [s][r]
  short8 qc[2][2]; floatx4 lc[2];
  stage(0, 0);
  loadQ(0, qc, lc);

#pragma unroll
  for (int p = 0; p < 8; ++p) {
    const int buf = p & 1;
    __syncthreads();                     // drains tile p's loads; buf 1-buf now free
    if (p < 7) stage(p + 1, 1 - buf);    // prefetch overlaps tile p's compute
    short8 qn[2][2]; floatx4 ln[2];
    loadQ(p < 7 ? p + 1 : 7, qn, ln);    // clamped; p==7 result unused
#pragma unroll
    for (int hh = 0; hh < 2; ++hh) {
      const char* tb = (const char*)smem[buf * 2 + hh];
#pragma unroll
      for (int s = 0; s < 4; ++s) {
        if (j0 + s * 16 > i0 + 15) continue;          // wave-uniform: fully masked
        const char* kr = tb + (s * 16 + lanem) * 128;
        short8 b0 = *(const short8*)(kr + (quad ^ swz) * 16);
        short8 b1 = *(const short8*)(kr + ((4 + quad) ^ swz) * 16);
        floatx4 sv = (floatx4){0.f, 0.f, 0.f, 0.f};
        sv = mfma16(qc[hh][0], b0, sv);
        sv = mfma16(qc[hh][1], b1, sv);
        if (j0 + s * 16 + 15 <= i0) {                 // fully unmasked
#pragma unroll
          for (int r = 0; r < 4; ++r)
            acc[s][r] += __expf(sv[r] * 0.125f) * lc[hh][r];
        } else {
#pragma unroll
          for (int r = 0; r < 4; ++r) {
            int irow = i0 + quad * 4 + r;
            int jc = j0 + s * 16 + lanem;
            if (jc <= irow) acc[s][r] += __expf(sv[r] * 0.125f) * lc[hh][r];
          }
        }
      }
    }
#pragma unroll
    for (int hh = 0; hh < 2; ++hh) {
      qc[hh][0] = qn[hh][0]; qc[hh][1] = qn[hh][1]; lc[hh] = ln[hh];
    }
  }

#pragma unroll
  for (int s = 0; s < 4; ++s)
#pragma unroll
    for (int r = 0; r < 4; ++r) {
      int irow = i0 + quad * 4 + r;
      int jc = j0 + s * 16 + lanem;
      ob[(size_t)irow * L_ + jc] = acc[s][r] * (1.0f / H_);
    }
}

// ---------------- host ----------------
extern "C" void kernel_launch(void* const* d_in, const int* in_sizes, int n_in,
                              void* d_out, int out_size, void* d_ws, size_t ws_size,
                              hipStream_t stream) {
  const float* query = (const float*)d_in[0];
  const float* key   = (const float*)d_in[1];
  const float* value = (const float*)d_in[2];
  const float* w_in  = (const float*)d_in[3];
  const float* b_in  = (const float*)d_in[4];
  const float* w_out = (const float*)d_in[5];
  const float* b_out = (const float*)d_in[6];

  char* ws = (char*)d_ws;
  size_t off = 0;
  auto alloc = [&](size_t bytes) -> void* {
    void* p = ws + off;
    off += (bytes + 255) & ~(size_t)255;
    return p;
  };
  u16* w_in_b  = (u16*)alloc((size_t)3 * E_ * K_ * 2);
  u16* w_out_b = (u16*)alloc((size_t)E_ * K_ * 2);
  u16* x_b     = (u16*)alloc((size_t)3 * M_ * K_ * 2);
  u16* qh      = (u16*)alloc((size_t)B_ * H_ * L_ * HD_ * 2);
  u16* kh      = (u16*)alloc((size_t)B_ * H_ * L_ * HD_ * 2);
  u16* vhT     = (u16*)alloc((size_t)B_ * H_ * L_ * HD_ * 2);
  u16* ctx     = (u16*)alloc((size_t)M_ * E_ * 2);
  float* li_ws = (float*)alloc((size_t)B_ * H_ * L_ * 4);

  // fp32 -> bf16, single launch for all 5 tensors
  convall<<<dim3(4096, 1, 5), 256, 0, stream>>>(
      query, key, value, w_in, w_out, x_b, w_in_b, w_out_b);

  // QKV projection
  gemm_qkv<<<dim3(E_ / 128, M_ / 128, 3), 256, 0, stream>>>(
      x_b, w_in_b, b_in, qh, kh, vhT);

  // flash attention -> ctx, 1/l (folded-triangle uniform blocks)
  attn1<<<dim3(L_ / 128, H_, B_), 256, 0, stream>>>(qh, kh, vhT, ctx, li_ws);

  // fused: head-averaged probs (z<2) + out projection (z==2)
  fused_tail<<<dim3(L_ / 64, L_ / 64, 3), 256, 0, stream>>>(
      qh, kh, li_ws, (float*)d_out + (size_t)M_ * E_,
      ctx, w_out_b, b_out, (float*)d_out);
}

// Round 10
// 264.996 us; speedup vs baseline: 1.2479x; 1.2479x over previous
//
#include <hip/hip_runtime.h>

#define L_ 2048
#define B_ 2
#define E_ 1024
#define H_ 16
#define HD_ 64
#define M_ 4096   // L_*B_
#define K_ 1024   // E_

typedef unsigned short u16;
typedef unsigned int u32;
using short8  = __attribute__((ext_vector_type(8))) short;
using short4v = __attribute__((ext_vector_type(4))) short;
using floatx4 = __attribute__((ext_vector_type(4))) float;

__device__ inline u16 f2b(float f) {            // fp32 -> bf16 RNE
  unsigned u = __float_as_uint(f);
  u += 0x7FFF + ((u >> 16) & 1);
  return (u16)(u >> 16);
}

// two fp32 -> packed bf16 pair, round-half-up
__device__ inline u32 pack2(float a, float b) {
  u32 ua = __float_as_uint(a) + 0x8000u;
  u32 ub = __float_as_uint(b) + 0x8000u;
  return (ua >> 16) | (ub & 0xFFFF0000u);
}

__device__ inline floatx4 mfma16(short8 a, short8 b, floatx4 c) {
  return __builtin_amdgcn_mfma_f32_16x16x32_bf16(a, b, c, 0, 0, 0);
}

// native 2^x: clang builtin lowering to a single v_exp_f32 WITH
// compiler-managed TRANS-use hazard handling (round-8's opaque inline asm
// lacked the hazard nops -> stale-register garbage; round-9's __exp2f was
// host-only and didn't compile). Softmax scale 0.125*log2(e) is folded into
// the q projection, so exp(S*0.125) == fexp2(S') with no per-element mul.
__device__ inline float fexp2(float x) { return __builtin_amdgcn_exp2f(x); }
#define QSCALE 0.1803368801111244f   // 0.125 * log2(e)

// async global->LDS, 16B per lane; lds dest is wave-uniform base + lane*16
__device__ inline void gload16(const void* g, void* l) {
  __builtin_amdgcn_global_load_lds(
      (const __attribute__((address_space(1))) u32*)g,
      (__attribute__((address_space(3))) u32*)l, 16, 0, 0);
}

// ---------------- fp32 -> bf16 conversion (all 5 tensors, one launch) ------
__global__ void convall(const float* __restrict__ q, const float* __restrict__ k,
                        const float* __restrict__ v, const float* __restrict__ wi,
                        const float* __restrict__ wo,
                        u16* __restrict__ xb, u16* __restrict__ wib,
                        u16* __restrict__ wob) {
  const int z = blockIdx.z;
  const float* src;
  u16* dst;
  int n4;
  if (z < 3)      { src = (z == 0 ? q : (z == 1 ? k : v));
                    dst = xb + (size_t)z * M_ * K_; n4 = M_ * K_ / 4; }
  else if (z == 3){ src = wi; dst = wib; n4 = 3 * E_ * K_ / 4; }
  else            { src = wo; dst = wob; n4 = E_ * K_ / 4; }
  int i = blockIdx.x * blockDim.x + threadIdx.x;
  if (i < n4) {
    float4 val = ((const float4*)src)[i];
    ushort4 o;
    o.x = f2b(val.x); o.y = f2b(val.y); o.z = f2b(val.z); o.w = f2b(val.w);
    ((ushort4*)dst)[i] = o;
  }
}

// ---------------- bf16 GEMM: C[M,N] = A[M,K] * W[N,K]^T + bias ----------------
// V is stored column-permuted within 32-col groups so attn1's PV A-frag is a
// single natural b128 read: pos(l) = ((l>>2)&3)*8 + ((l>>4)&1)*4 + (l&3).
// Double-buffered LDS staging, ONE barrier per K-step.
// MODE 0, p==0 (q projection): output scaled by QSCALE so downstream softmax
// exp(S*0.125) becomes a bare v_exp_f32 (2^x).
template <int MODE>
__global__ __launch_bounds__(256) void gemm128(
    const u16* __restrict__ A, const u16* __restrict__ W, const float* __restrict__ bias,
    u16* __restrict__ qh, u16* __restrict__ kh, u16* __restrict__ vhT,
    float* __restrict__ outp)
{
  __shared__ __align__(16) u16 As[2][128 * 32];
  __shared__ __align__(16) u16 Bs[2][128 * 32];
  const int p = (MODE == 0) ? blockIdx.z : 0;
  const u16* Ap = A + (size_t)p * M_ * K_;
  const u16* Wp = W + (size_t)p * E_ * K_;
  const float* bp = bias + p * E_;
  const int row0 = blockIdx.y * 128, col0 = blockIdx.x * 128;
  const int t = threadIdx.x, lane = t & 63, wv = t >> 6;
  const int lanem = lane & 15, quad = lane >> 4;
  const int wm = wv >> 1, wn = wv & 1;

  int f0 = t, f1 = 256 + t;
  int r0s = f0 >> 2, q0s = (f0 & 3) ^ ((r0s >> 1) & 3);
  int r1s = f1 >> 2, q1s = (f1 & 3) ^ ((r1s >> 1) & 3);

  floatx4 acc[4][4];
#pragma unroll
  for (int mi = 0; mi < 4; ++mi)
#pragma unroll
    for (int ni = 0; ni < 4; ++ni) acc[mi][ni] = (floatx4){0.f, 0.f, 0.f, 0.f};

  const int swz = (lanem >> 1) & 3;

  auto STAGE = [&](int buf, int k0) {
    gload16(Ap + (size_t)(row0 + r0s) * K_ + k0 + q0s * 8, (char*)As[buf] + wv * 1024);
    gload16(Wp + (size_t)(col0 + r0s) * K_ + k0 + q0s * 8, (char*)Bs[buf] + wv * 1024);
    gload16(Ap + (size_t)(row0 + r1s) * K_ + k0 + q1s * 8, (char*)As[buf] + 4096 + wv * 1024);
    gload16(Wp + (size_t)(col0 + r1s) * K_ + k0 + q1s * 8, (char*)Bs[buf] + 4096 + wv * 1024);
  };

  STAGE(0, 0);                               // preload tile 0
  for (int k0 = 0; k0 < K_; k0 += 32) {
    const int buf = (k0 >> 5) & 1;
    __syncthreads();                         // drains tile k0's loads; other buf free
    if (k0 + 32 < K_) STAGE(buf ^ 1, k0 + 32);
    short8 af[4], bfg[4];
#pragma unroll
    for (int mi = 0; mi < 4; ++mi) {
      int r = wm * 64 + mi * 16 + lanem;
      af[mi] = *(const short8*)((const char*)As[buf] + r * 64 + (quad ^ swz) * 16);
    }
#pragma unroll
    for (int ni = 0; ni < 4; ++ni) {
      int r = wn * 64 + ni * 16 + lanem;
      bfg[ni] = *(const short8*)((const char*)Bs[buf] + r * 64 + (quad ^ swz) * 16);
    }
#pragma unroll
    for (int mi = 0; mi < 4; ++mi)
#pragma unroll
      for (int ni = 0; ni < 4; ++ni)
        acc[mi][ni] = mfma16(af[mi], bfg[ni], acc[mi][ni]);
  }

#pragma unroll
  for (int ni = 0; ni < 4; ++ni) {
    int gc = col0 + wn * 64 + ni * 16 + lanem;
    float bv = bp[gc];
#pragma unroll
    for (int mi = 0; mi < 4; ++mi) {
      int gr0 = row0 + wm * 64 + mi * 16 + quad * 4;
#pragma unroll
      for (int v = 0; v < 4; ++v) {
        float val = acc[mi][ni][v] + bv;
        if (MODE == 0 && p == 0) val *= QSCALE;
        int r = gr0 + v;
        if (MODE == 1) {
          outp[(size_t)r * E_ + gc] = val;
        } else {
          int l = r >> 1, bb = r & 1, hh = gc >> 6, d = gc & 63;
          u16 x = f2b(val);
          if (p == 0)      qh[(((size_t)bb * H_ + hh) * L_ + l) * HD_ + d] = x;
          else if (p == 1) kh[(((size_t)bb * H_ + hh) * L_ + l) * HD_ + d] = x;
          else {
            int lp = (l & ~31) | (((l >> 2) & 3) * 8 + ((l >> 4) & 1) * 4 + (l & 3));
            vhT[(((size_t)bb * H_ + hh) * HD_ + d) * L_ + lp] = x;
          }
        }
      }
    }
  }
}

// ---------------- flash attention: folded-triangle blocks, dbuf staging ----------------
__global__ __launch_bounds__(256, 2) void attn1(
    const u16* __restrict__ qh, const u16* __restrict__ kh, const u16* __restrict__ vhT,
    u16* __restrict__ ctx, float* __restrict__ li_ws)
{
  __shared__ __align__(16) u16 Ks[2][64 * 64];
  __shared__ __align__(16) u16 Vs[2][64 * 64];
  const int g = blockIdx.x;                    // 0..15
  const int h = blockIdx.y, b = blockIdx.z;
  const int t = threadIdx.x, lane = t & 63, wv = t >> 6;
  const int lanem = lane & 15, quad = lane >> 4;
  const int bh = b * H_ + h;
  const int gB = (L_ / 64 - 1) - g;            // 31-g
  const int rowA = g * 64 + wv * 16 + lanem;
  const int rowB = gB * 64 + wv * 16 + lanem;

  const u16* qpA = qh + ((size_t)bh * L_ + rowA) * HD_;
  const u16* qpB = qh + ((size_t)bh * L_ + rowB) * HD_;
  short8 qA0 = *(const short8*)(qpA + quad * 8);
  short8 qA1 = *(const short8*)(qpA + 32 + quad * 8);
  short8 qB0 = *(const short8*)(qpB + quad * 8);
  short8 qB1 = *(const short8*)(qpB + 32 + quad * 8);

  const int srow = lane >> 3;
  const int spiece = (lane & 7) ^ srow;
  const u16* ksrc = kh + ((size_t)bh * L_ + wv * 16 + srow) * HD_ + spiece * 8;
  const u16* vsrc = vhT + ((size_t)bh * HD_ + wv * 16 + srow) * L_ + spiece * 8;

  const int ntiles = 32 - g;
  auto stage = [&](int buf) {
    gload16(ksrc, (char*)Ks[buf] + wv * 2048);
    gload16(ksrc + 8 * HD_, (char*)Ks[buf] + wv * 2048 + 1024);
    gload16(vsrc, (char*)Vs[buf] + wv * 2048);
    gload16(vsrc + (size_t)8 * L_, (char*)Vs[buf] + wv * 2048 + 1024);
    ksrc += 64 * HD_;
    vsrc += 64;
  };

  const int swz = lanem & 7;
  const int cb0 = lanem * 128 + ((quad ^ swz)) * 16;
  const int cb1 = lanem * 128 + ((quad ^ swz) ^ 4) * 16;

  float liA = 0.f, liB = 0.f;
  floatx4 oA[4], oB[4];
#pragma unroll
  for (int d = 0; d < 4; ++d) { oA[d] = (floatx4){0.f,0.f,0.f,0.f}; oB[d] = oA[d]; }

  int j0 = 0, tcur = 0;

  auto do_tile = [&](int modeA, int modeB) {
    __syncthreads();                      // drains tile tcur's loads; prev buf free
    if (tcur + 1 < ntiles) stage((tcur + 1) & 1);
    const char* kbuf = (const char*)Ks[tcur & 1];
    const char* vbuf = (const char*)Vs[tcur & 1];

    floatx4 sA[4], sB[4];
#pragma unroll
    for (int jf = 0; jf < 4; ++jf) {
      short8 a0 = *(const short8*)(kbuf + cb0 + jf * 2048);
      short8 a1 = *(const short8*)(kbuf + cb1 + jf * 2048);
      floatx4 z = (floatx4){0.f,0.f,0.f,0.f};
      if (modeA != 2) sA[jf] = mfma16(a1, qA1, mfma16(a0, qA0, z));
      sB[jf] = mfma16(a1, qB1, mfma16(a0, qB0, z));
    }

    short8 pbA[2], pbB[2];
    auto soft = [&](floatx4* st, int row, float& li, short8* pb, int masked) {
#pragma unroll
      for (int jc = 0; jc < 2; ++jc) {
        float p[8];
#pragma unroll
        for (int r = 0; r < 4; ++r) {
          int ja = j0 + jc * 32 + quad * 4 + r;
          float e0 = fexp2(st[jc * 2][r]);
          float e1 = fexp2(st[jc * 2 + 1][r]);
          if (masked) {
            e0 = (ja <= row) ? e0 : 0.f;
            e1 = (ja + 16 <= row) ? e1 : 0.f;
          }
          li += e0 + e1;
          p[r] = e0; p[4 + r] = e1;
        }
        union { u32 w[4]; short8 s; } u;
        u.w[0] = pack2(p[0], p[1]); u.w[1] = pack2(p[2], p[3]);
        u.w[2] = pack2(p[4], p[5]); u.w[3] = pack2(p[6], p[7]);
        pb[jc] = u.s;
      }
    };
    if (modeA == 0) soft(sA, rowA, liA, pbA, 0);
    else if (modeA == 1) soft(sA, rowA, liA, pbA, 1);
    if (modeB == 0) soft(sB, rowB, liB, pbB, 0);
    else soft(sB, rowB, liB, pbB, 1);

#pragma unroll
    for (int jc = 0; jc < 2; ++jc) {
      const int base = (jc == 0) ? cb0 : cb1;
#pragma unroll
      for (int dbl = 0; dbl < 4; ++dbl) {
        short8 vf = *(const short8*)(vbuf + base + dbl * 2048);
        if (modeA != 2) oA[dbl] = mfma16(vf, pbA[jc], oA[dbl]);
        oB[dbl] = mfma16(vf, pbB[jc], oB[dbl]);
      }
    }
    j0 += 64;
    ++tcur;
  };

  stage(0);                                   // preload tile 0
  for (int jt = 0; jt < g; ++jt) do_tile(0, 0);   // both groups, unmasked
  do_tile(1, 0);                                  // A diagonal, B unmasked
  for (int jt = g + 1; jt <= 30 - g; ++jt) do_tile(2, 0);  // B only
  do_tile(2, 1);                                  // B diagonal

  liA += __shfl_xor(liA, 16); liA += __shfl_xor(liA, 32);
  liB += __shfl_xor(liB, 16); liB += __shfl_xor(liB, 32);
  float invA = 1.0f / liA, invB = 1.0f / liB;

  u16* cA = ctx + ((size_t)rowA * B_ + b) * E_ + h * HD_ + quad * 4;
  u16* cB = ctx + ((size_t)rowB * B_ + b) * E_ + h * HD_ + quad * 4;
#pragma unroll
  for (int dbl = 0; dbl < 4; ++dbl) {
    ushort4 pkA, pkB;
    pkA.x = f2b(oA[dbl][0] * invA); pkA.y = f2b(oA[dbl][1] * invA);
    pkA.z = f2b(oA[dbl][2] * invA); pkA.w = f2b(oA[dbl][3] * invA);
    pkB.x = f2b(oB[dbl][0] * invB); pkB.y = f2b(oB[dbl][1] * invB);
    pkB.z = f2b(oB[dbl][2] * invB); pkB.w = f2b(oB[dbl][3] * invB);
    *(ushort4*)(cA + dbl * 16) = pkA;
    *(ushort4*)(cB + dbl * 16) = pkB;
  }
  if (quad == 0) {
    li_ws[(size_t)bh * L_ + rowA] = invA;
    li_ws[(size_t)bh * L_ + rowB] = invB;
  }
}

// ---------------- head-averaged attention probs (v7: 16 phases x 1 head, 16KB) ----
// v1 (32KB, 2 heads/phase) pinned at 52us with occupancy 16.7% (5 blocks/CU);
// v3 (64KB) was worse at 9%. Inverting: 1 head per phase, 2x8KB buffers ->
// 16KB LDS -> 8 blocks/CU (thread-cap), ~2x resident waves to overlap the
// per-phase barrier drains. Same verified stage/read swizzle; exp via native
// v_exp_f32 builtin (scale folded into qh).
__global__ __launch_bounds__(256) void attn2(
    const u16* __restrict__ qh, const u16* __restrict__ kh,
    const float* __restrict__ li_ws, float* __restrict__ out2)
{
  __shared__ __align__(16) u16 Ks[2][64 * 64];   // 16 KB total
  const int jt = blockIdx.x, it = blockIdx.y, b = blockIdx.z;
  const int t = threadIdx.x, lane = t & 63, wv = t >> 6;
  const int lanem = lane & 15, quad = lane >> 4;
  const int i0 = it * 64 + wv * 16;
  const int j0 = jt * 64;
  float* ob = out2 + (size_t)b * L_ * L_;

  if (jt > it) {          // strictly upper block: zeros (d_out is poisoned)
    float4 z = {0.f, 0.f, 0.f, 0.f};
    float* rp = ob + (size_t)(i0 + lanem) * L_ + j0 + quad * 16;
    ((float4*)rp)[0] = z; ((float4*)rp)[1] = z;
    ((float4*)rp)[2] = z; ((float4*)rp)[3] = z;
    return;
  }

  const int srow = lane >> 3;
  const int spiece = (lane & 7) ^ srow;
  const int swz = lanem & 7;

  auto stage = [&](int h, int buf) {
    const u16* kg = kh + ((size_t)(b * H_ + h) * L_ + j0) * HD_;
#pragma unroll
    for (int k = wv * 2; k < wv * 2 + 2; ++k)
      gload16(kg + (size_t)(k * 8 + srow) * HD_ + spiece * 8,
              (char*)Ks[buf] + k * 1024);
  };
  auto loadQ = [&](int h, short8 q[2], floatx4& lf) {
    int bh = b * H_ + h;
    const u16* qb = qh + ((size_t)bh * L_ + i0 + lanem) * HD_;
    q[0] = *(const short8*)(qb + quad * 8);
    q[1] = *(const short8*)(qb + 32 + quad * 8);
    lf = *(const floatx4*)(li_ws + (size_t)bh * L_ + i0 + quad * 4);
  };

  float acc[4][4] = {};   // [s][r]
  short8 qc[2]; floatx4 lc;
  stage(0, 0);
  loadQ(0, qc, lc);

#pragma unroll
  for (int p = 0; p < 16; ++p) {
    const int buf = p & 1;
    __syncthreads();                     // drains head p's loads; buf^1 now free
    if (p < 15) stage(p + 1, buf ^ 1);   // prefetch overlaps head p's compute
    short8 qn[2]; floatx4 ln;
    loadQ(p < 15 ? p + 1 : 15, qn, ln);  // clamped; p==15 result unused
    const char* tb = (const char*)Ks[buf];
#pragma unroll
    for (int s = 0; s < 4; ++s) {
      if (j0 + s * 16 > i0 + 15) continue;          // wave-uniform: fully masked
      const char* kr = tb + (s * 16 + lanem) * 128;
      short8 b0 = *(const short8*)(kr + (quad ^ swz) * 16);
      short8 b1 = *(const short8*)(kr + ((4 + quad) ^ swz) * 16);
      floatx4 sv = (floatx4){0.f, 0.f, 0.f, 0.f};
      sv = mfma16(qc[0], b0, sv);
      sv = mfma16(qc[1], b1, sv);
      if (j0 + s * 16 + 15 <= i0) {                 // fully unmasked
#pragma unroll
        for (int r = 0; r < 4; ++r)
          acc[s][r] += fexp2(sv[r]) * lc[r];
      } else {
#pragma unroll
        for (int r = 0; r < 4; ++r) {
          int irow = i0 + quad * 4 + r;
          int jc = j0 + s * 16 + lanem;
          if (jc <= irow) acc[s][r] += fexp2(sv[r]) * lc[r];
        }
      }
    }
    qc[0] = qn[0]; qc[1] = qn[1]; lc = ln;
  }

#pragma unroll
  for (int s = 0; s < 4; ++s)
#pragma unroll
    for (int r = 0; r < 4; ++r) {
      int irow = i0 + quad * 4 + r;
      int jc = j0 + s * 16 + lanem;
      ob[(size_t)irow * L_ + jc] = acc[s][r] * (1.0f / H_);
    }
}

// ---------------- host ----------------
extern "C" void kernel_launch(void* const* d_in, const int* in_sizes, int n_in,
                              void* d_out, int out_size, void* d_ws, size_t ws_size,
                              hipStream_t stream) {
  const float* query = (const float*)d_in[0];
  const float* key   = (const float*)d_in[1];
  const float* value = (const float*)d_in[2];
  const float* w_in  = (const float*)d_in[3];
  const float* b_in  = (const float*)d_in[4];
  const float* w_out = (const float*)d_in[5];
  const float* b_out = (const float*)d_in[6];

  char* ws = (char*)d_ws;
  size_t off = 0;
  auto alloc = [&](size_t bytes) -> void* {
    void* p = ws + off;
    off += (bytes + 255) & ~(size_t)255;
    return p;
  };
  u16* w_in_b  = (u16*)alloc((size_t)3 * E_ * K_ * 2);
  u16* w_out_b = (u16*)alloc((size_t)E_ * K_ * 2);
  u16* x_b     = (u16*)alloc((size_t)3 * M_ * K_ * 2);
  u16* qh      = (u16*)alloc((size_t)B_ * H_ * L_ * HD_ * 2);
  u16* kh      = (u16*)alloc((size_t)B_ * H_ * L_ * HD_ * 2);
  u16* vhT     = (u16*)alloc((size_t)B_ * H_ * L_ * HD_ * 2);
  u16* ctx     = (u16*)alloc((size_t)M_ * E_ * 2);
  float* li_ws = (float*)alloc((size_t)B_ * H_ * L_ * 4);

  // fp32 -> bf16, single launch for all 5 tensors
  convall<<<dim3(4096, 1, 5), 256, 0, stream>>>(
      query, key, value, w_in, w_out, x_b, w_in_b, w_out_b);

  // QKV projection (q output pre-scaled by QSCALE)
  gemm128<0><<<dim3(E_ / 128, M_ / 128, 3), 256, 0, stream>>>(
      x_b, w_in_b, b_in, qh, kh, vhT, nullptr);

  // flash attention -> ctx, 1/l (folded-triangle uniform blocks)
  attn1<<<dim3(L_ / 128, H_, B_), 256, 0, stream>>>(qh, kh, vhT, ctx, li_ws);

  // head-averaged probs -> second output
  attn2<<<dim3(L_ / 64, L_ / 64, B_), 256, 0, stream>>>(
      qh, kh, li_ws, (float*)d_out + (size_t)M_ * E_);

  // out projection -> first output
  gemm128<1><<<dim3(E_ / 128, M_ / 128, 1), 256, 0, stream>>>(
      ctx, w_out_b, b_out, nullptr, nullptr, nullptr, (float*)d_out);
}

// Round 12
// 262.030 us; speedup vs baseline: 1.2620x; 1.0113x over previous
//
#include <hip/hip_runtime.h>

#define L_ 2048
#define B_ 2
#define E_ 1024
#define H_ 16
#define HD_ 64
#define M_ 4096   // L_*B_
#define K_ 1024   // E_

typedef unsigned short u16;
typedef unsigned int u32;
using short8  = __attribute__((ext_vector_type(8))) short;
using short4v = __attribute__((ext_vector_type(4))) short;
using floatx4 = __attribute__((ext_vector_type(4))) float;

__device__ inline u16 f2b(float f) {            // fp32 -> bf16 RNE
  unsigned u = __float_as_uint(f);
  u += 0x7FFF + ((u >> 16) & 1);
  return (u16)(u >> 16);
}

// two fp32 -> packed bf16 pair, round-half-up
__device__ inline u32 pack2(float a, float b) {
  u32 ua = __float_as_uint(a) + 0x8000u;
  u32 ub = __float_as_uint(b) + 0x8000u;
  return (ua >> 16) | (ub & 0xFFFF0000u);
}

__device__ inline floatx4 mfma16(short8 a, short8 b, floatx4 c) {
  return __builtin_amdgcn_mfma_f32_16x16x32_bf16(a, b, c, 0, 0, 0);
}

// native 2^x via clang builtin (single v_exp_f32 with compiler-managed
// TRANS-use hazard handling). Softmax scale 0.125*log2(e) is folded into
// the q projection, so exp(S*0.125) == fexp2(S') with no per-element mul.
__device__ inline float fexp2(float x) { return __builtin_amdgcn_exp2f(x); }
#define QSCALE 0.1803368801111244f   // 0.125 * log2(e)

// async global->LDS, 16B per lane; lds dest is wave-uniform base + lane*16
__device__ inline void gload16(const void* g, void* l) {
  __builtin_amdgcn_global_load_lds(
      (const __attribute__((address_space(1))) u32*)g,
      (__attribute__((address_space(3))) u32*)l, 16, 0, 0);
}

// ---------------- fp32 -> bf16 conversion (all 5 tensors, one launch) ------
__global__ void convall(const float* __restrict__ q, const float* __restrict__ k,
                        const float* __restrict__ v, const float* __restrict__ wi,
                        const float* __restrict__ wo,
                        u16* __restrict__ xb, u16* __restrict__ wib,
                        u16* __restrict__ wob) {
  const int z = blockIdx.z;
  const float* src;
  u16* dst;
  int n4;
  if (z < 3)      { src = (z == 0 ? q : (z == 1 ? k : v));
                    dst = xb + (size_t)z * M_ * K_; n4 = M_ * K_ / 4; }
  else if (z == 3){ src = wi; dst = wib; n4 = 3 * E_ * K_ / 4; }
  else            { src = wo; dst = wob; n4 = E_ * K_ / 4; }
  int i = blockIdx.x * blockDim.x + threadIdx.x;
  if (i < n4) {
    float4 val = ((const float4*)src)[i];
    ushort4 o;
    o.x = f2b(val.x); o.y = f2b(val.y); o.z = f2b(val.z); o.w = f2b(val.w);
    ((ushort4*)dst)[i] = o;
  }
}

// ---------------- bf16 GEMM: C[M,N] = A[M,K] * W[N,K]^T + bias ----------------
// V is stored column-permuted within 32-col groups so attn1's PV A-frag is a
// single natural b128 read: pos(l) = ((l>>2)&3)*8 + ((l>>4)&1)*4 + (l&3).
// Double-buffered LDS staging, ONE barrier per K-step.
// MODE 0, p==0 (q projection): output scaled by QSCALE so downstream softmax
// exp(S*0.125) becomes a bare v_exp_f32 (2^x).
template <int MODE>
__global__ __launch_bounds__(256) void gemm128(
    const u16* __restrict__ A, const u16* __restrict__ W, const float* __restrict__ bias,
    u16* __restrict__ qh, u16* __restrict__ kh, u16* __restrict__ vhT,
    float* __restrict__ outp)
{
  __shared__ __align__(16) u16 As[2][128 * 32];
  __shared__ __align__(16) u16 Bs[2][128 * 32];
  const int p = (MODE == 0) ? blockIdx.z : 0;
  const u16* Ap = A + (size_t)p * M_ * K_;
  const u16* Wp = W + (size_t)p * E_ * K_;
  const float* bp = bias + p * E_;
  const int row0 = blockIdx.y * 128, col0 = blockIdx.x * 128;
  const int t = threadIdx.x, lane = t & 63, wv = t >> 6;
  const int lanem = lane & 15, quad = lane >> 4;
  const int wm = wv >> 1, wn = wv & 1;

  int f0 = t, f1 = 256 + t;
  int r0s = f0 >> 2, q0s = (f0 & 3) ^ ((r0s >> 1) & 3);
  int r1s = f1 >> 2, q1s = (f1 & 3) ^ ((r1s >> 1) & 3);

  floatx4 acc[4][4];
#pragma unroll
  for (int mi = 0; mi < 4; ++mi)
#pragma unroll
    for (int ni = 0; ni < 4; ++ni) acc[mi][ni] = (floatx4){0.f, 0.f, 0.f, 0.f};

  const int swz = (lanem >> 1) & 3;

  auto STAGE = [&](int buf, int k0) {
    gload16(Ap + (size_t)(row0 + r0s) * K_ + k0 + q0s * 8, (char*)As[buf] + wv * 1024);
    gload16(Wp + (size_t)(col0 + r0s) * K_ + k0 + q0s * 8, (char*)Bs[buf] + wv * 1024);
    gload16(Ap + (size_t)(row0 + r1s) * K_ + k0 + q1s * 8, (char*)As[buf] + 4096 + wv * 1024);
    gload16(Wp + (size_t)(col0 + r1s) * K_ + k0 + q1s * 8, (char*)Bs[buf] + 4096 + wv * 1024);
  };

  STAGE(0, 0);                               // preload tile 0
  for (int k0 = 0; k0 < K_; k0 += 32) {
    const int buf = (k0 >> 5) & 1;
    __syncthreads();                         // drains tile k0's loads; other buf free
    if (k0 + 32 < K_) STAGE(buf ^ 1, k0 + 32);
    short8 af[4], bfg[4];
#pragma unroll
    for (int mi = 0; mi < 4; ++mi) {
      int r = wm * 64 + mi * 16 + lanem;
      af[mi] = *(const short8*)((const char*)As[buf] + r * 64 + (quad ^ swz) * 16);
    }
#pragma unroll
    for (int ni = 0; ni < 4; ++ni) {
      int r = wn * 64 + ni * 16 + lanem;
      bfg[ni] = *(const short8*)((const char*)Bs[buf] + r * 64 + (quad ^ swz) * 16);
    }
#pragma unroll
    for (int mi = 0; mi < 4; ++mi)
#pragma unroll
      for (int ni = 0; ni < 4; ++ni)
        acc[mi][ni] = mfma16(af[mi], bfg[ni], acc[mi][ni]);
  }

#pragma unroll
  for (int ni = 0; ni < 4; ++ni) {
    int gc = col0 + wn * 64 + ni * 16 + lanem;
    float bv = bp[gc];
#pragma unroll
    for (int mi = 0; mi < 4; ++mi) {
      int gr0 = row0 + wm * 64 + mi * 16 + quad * 4;
#pragma unroll
      for (int v = 0; v < 4; ++v) {
        float val = acc[mi][ni][v] + bv;
        if (MODE == 0 && p == 0) val *= QSCALE;
        int r = gr0 + v;
        if (MODE == 1) {
          outp[(size_t)r * E_ + gc] = val;
        } else {
          int l = r >> 1, bb = r & 1, hh = gc >> 6, d = gc & 63;
          u16 x = f2b(val);
          if (p == 0)      qh[(((size_t)bb * H_ + hh) * L_ + l) * HD_ + d] = x;
          else if (p == 1) kh[(((size_t)bb * H_ + hh) * L_ + l) * HD_ + d] = x;
          else {
            int lp = (l & ~31) | (((l >> 2) & 3) * 8 + ((l >> 4) & 1) * 4 + (l & 3));
            vhT[(((size_t)bb * H_ + hh) * HD_ + d) * L_ + lp] = x;
          }
        }
      }
    }
  }
}

// ---------------- flash attention: folded-triangle blocks, dbuf staging ----------------
__global__ __launch_bounds__(256, 2) void attn1(
    const u16* __restrict__ qh, const u16* __restrict__ kh, const u16* __restrict__ vhT,
    u16* __restrict__ ctx, float* __restrict__ li_ws)
{
  __shared__ __align__(16) u16 Ks[2][64 * 64];
  __shared__ __align__(16) u16 Vs[2][64 * 64];
  const int g = blockIdx.x;                    // 0..15
  const int h = blockIdx.y, b = blockIdx.z;
  const int t = threadIdx.x, lane = t & 63, wv = t >> 6;
  const int lanem = lane & 15, quad = lane >> 4;
  const int bh = b * H_ + h;
  const int gB = (L_ / 64 - 1) - g;            // 31-g
  const int rowA = g * 64 + wv * 16 + lanem;
  const int rowB = gB * 64 + wv * 16 + lanem;

  const u16* qpA = qh + ((size_t)bh * L_ + rowA) * HD_;
  const u16* qpB = qh + ((size_t)bh * L_ + rowB) * HD_;
  short8 qA0 = *(const short8*)(qpA + quad * 8);
  short8 qA1 = *(const short8*)(qpA + 32 + quad * 8);
  short8 qB0 = *(const short8*)(qpB + quad * 8);
  short8 qB1 = *(const short8*)(qpB + 32 + quad * 8);

  const int srow = lane >> 3;
  const int spiece = (lane & 7) ^ srow;
  const u16* ksrc = kh + ((size_t)bh * L_ + wv * 16 + srow) * HD_ + spiece * 8;
  const u16* vsrc = vhT + ((size_t)bh * HD_ + wv * 16 + srow) * L_ + spiece * 8;

  const int ntiles = 32 - g;
  auto stage = [&](int buf) {
    gload16(ksrc, (char*)Ks[buf] + wv * 2048);
    gload16(ksrc + 8 * HD_, (char*)Ks[buf] + wv * 2048 + 1024);
    gload16(vsrc, (char*)Vs[buf] + wv * 2048);
    gload16(vsrc + (size_t)8 * L_, (char*)Vs[buf] + wv * 2048 + 1024);
    ksrc += 64 * HD_;
    vsrc += 64;
  };

  const int swz = lanem & 7;
  const int cb0 = lanem * 128 + ((quad ^ swz)) * 16;
  const int cb1 = lanem * 128 + ((quad ^ swz) ^ 4) * 16;

  float liA = 0.f, liB = 0.f;
  floatx4 oA[4], oB[4];
#pragma unroll
  for (int d = 0; d < 4; ++d) { oA[d] = (floatx4){0.f,0.f,0.f,0.f}; oB[d] = oA[d]; }

  int j0 = 0, tcur = 0;

  auto do_tile = [&](int modeA, int modeB) {
    __syncthreads();                      // drains tile tcur's loads; prev buf free
    if (tcur + 1 < ntiles) stage((tcur + 1) & 1);
    const char* kbuf = (const char*)Ks[tcur & 1];
    const char* vbuf = (const char*)Vs[tcur & 1];

    floatx4 sA[4], sB[4];
#pragma unroll
    for (int jf = 0; jf < 4; ++jf) {
      short8 a0 = *(const short8*)(kbuf + cb0 + jf * 2048);
      short8 a1 = *(const short8*)(kbuf + cb1 + jf * 2048);
      floatx4 z = (floatx4){0.f,0.f,0.f,0.f};
      if (modeA != 2) sA[jf] = mfma16(a1, qA1, mfma16(a0, qA0, z));
      sB[jf] = mfma16(a1, qB1, mfma16(a0, qB0, z));
    }

    short8 pbA[2], pbB[2];
    auto soft = [&](floatx4* st, int row, float& li, short8* pb, int masked) {
#pragma unroll
      for (int jc = 0; jc < 2; ++jc) {
        float p[8];
#pragma unroll
        for (int r = 0; r < 4; ++r) {
          int ja = j0 + jc * 32 + quad * 4 + r;
          float e0 = fexp2(st[jc * 2][r]);
          float e1 = fexp2(st[jc * 2 + 1][r]);
          if (masked) {
            e0 = (ja <= row) ? e0 : 0.f;
            e1 = (ja + 16 <= row) ? e1 : 0.f;
          }
          li += e0 + e1;
          p[r] = e0; p[4 + r] = e1;
        }
        union { u32 w[4]; short8 s; } u;
        u.w[0] = pack2(p[0], p[1]); u.w[1] = pack2(p[2], p[3]);
        u.w[2] = pack2(p[4], p[5]); u.w[3] = pack2(p[6], p[7]);
        pb[jc] = u.s;
      }
    };
    if (modeA == 0) soft(sA, rowA, liA, pbA, 0);
    else if (modeA == 1) soft(sA, rowA, liA, pbA, 1);
    if (modeB == 0) soft(sB, rowB, liB, pbB, 0);
    else soft(sB, rowB, liB, pbB, 1);

#pragma unroll
    for (int jc = 0; jc < 2; ++jc) {
      const int base = (jc == 0) ? cb0 : cb1;
#pragma unroll
      for (int dbl = 0; dbl < 4; ++dbl) {
        short8 vf = *(const short8*)(vbuf + base + dbl * 2048);
        if (modeA != 2) oA[dbl] = mfma16(vf, pbA[jc], oA[dbl]);
        oB[dbl] = mfma16(vf, pbB[jc], oB[dbl]);
      }
    }
    j0 += 64;
    ++tcur;
  };

  stage(0);                                   // preload tile 0
  for (int jt = 0; jt < g; ++jt) do_tile(0, 0);   // both groups, unmasked
  do_tile(1, 0);                                  // A diagonal, B unmasked
  for (int jt = g + 1; jt <= 30 - g; ++jt) do_tile(2, 0);  // B only
  do_tile(2, 1);                                  // B diagonal

  liA += __shfl_xor(liA, 16); liA += __shfl_xor(liA, 32);
  liB += __shfl_xor(liB, 16); liB += __shfl_xor(liB, 32);
  float invA = 1.0f / liA, invB = 1.0f / liB;

  u16* cA = ctx + ((size_t)rowA * B_ + b) * E_ + h * HD_ + quad * 4;
  u16* cB = ctx + ((size_t)rowB * B_ + b) * E_ + h * HD_ + quad * 4;
#pragma unroll
  for (int dbl = 0; dbl < 4; ++dbl) {
    ushort4 pkA, pkB;
    pkA.x = f2b(oA[dbl][0] * invA); pkA.y = f2b(oA[dbl][1] * invA);
    pkA.z = f2b(oA[dbl][2] * invA); pkA.w = f2b(oA[dbl][3] * invA);
    pkB.x = f2b(oB[dbl][0] * invB); pkB.y = f2b(oB[dbl][1] * invB);
    pkB.z = f2b(oB[dbl][2] * invB); pkB.w = f2b(oB[dbl][3] * invB);
    *(ushort4*)(cA + dbl * 16) = pkA;
    *(ushort4*)(cB + dbl * 16) = pkB;
  }
  if (quad == 0) {
    li_ws[(size_t)bh * L_ + rowA] = invA;
    li_ws[(size_t)bh * L_ + rowB] = invB;
  }
}

// ---------------- head-averaged attention probs (v8: 128x128 tiles) ----
// Five schedule variants at 64x64 all pinned at 52-67us with no pipe >25%
// busy: per-phase useful work (~350cy/wave) is dwarfed by barrier/drain
// overhead, and per-output traffic is 2x what a 128-tile needs. v8: 128x128
// block, 4 waves x (32i x 128j) each; one 16KB K-stage serves 128 i-rows
// (K traffic halved, 287->141 MB total), 32 MFMA + 64 exp per wave-phase
// (~4x amortization per barrier). Stage/read swizzle and diagonal-mask
// predicates ported verbatim from the verified v7/v3 code with the row
// base generalized (ib = i0 + wv*32 + mi*16).
__global__ __launch_bounds__(256) void attn2(
    const u16* __restrict__ qh, const u16* __restrict__ kh,
    const float* __restrict__ li_ws, float* __restrict__ out2)
{
  __shared__ __align__(16) u16 Ks[2][128 * 64];   // 32 KB
  const int jt = blockIdx.x, it = blockIdx.y, b = blockIdx.z;
  const int t = threadIdx.x, lane = t & 63, wv = t >> 6;
  const int lanem = lane & 15, quad = lane >> 4;
  const int i0 = it * 128;
  const int j0 = jt * 128;
  float* ob = out2 + (size_t)b * L_ * L_;

  if (jt > it) {          // fully masked 128x128 block: zeros (d_out poisoned)
    float4 z = {0.f, 0.f, 0.f, 0.f};
#pragma unroll
    for (int ih = 0; ih < 2; ++ih)
#pragma unroll
      for (int jh = 0; jh < 2; ++jh) {
        float* rp = ob + (size_t)(i0 + ih * 64 + wv * 16 + lanem) * L_
                       + j0 + jh * 64 + quad * 16;
        ((float4*)rp)[0] = z; ((float4*)rp)[1] = z;
        ((float4*)rp)[2] = z; ((float4*)rp)[3] = z;
      }
    return;
  }

  const int srow = lane >> 3;
  const int spiece = (lane & 7) ^ srow;
  const int swz = lanem & 7;

  auto stage = [&](int h, int buf) {
    const u16* kg = kh + ((size_t)(b * H_ + h) * L_ + j0) * HD_;
#pragma unroll
    for (int k = wv * 4; k < wv * 4 + 4; ++k)
      gload16(kg + (size_t)(k * 8 + srow) * HD_ + spiece * 8,
              (char*)Ks[buf] + k * 1024);
  };
  auto loadQ = [&](int h, short8 q[2][2], floatx4 lf[2]) {
    int bh = b * H_ + h;
#pragma unroll
    for (int mi = 0; mi < 2; ++mi) {
      const u16* qb = qh + ((size_t)bh * L_ + i0 + wv * 32 + mi * 16 + lanem) * HD_;
      q[mi][0] = *(const short8*)(qb + quad * 8);
      q[mi][1] = *(const short8*)(qb + 32 + quad * 8);
      lf[mi] = *(const floatx4*)(li_ws + (size_t)bh * L_ + i0 + wv * 32 + mi * 16 + quad * 4);
    }
  };

  float acc[2][8][4] = {};   // [mi][s][r], all-static indexing
  short8 qc[2][2]; floatx4 lc[2];
  stage(0, 0);
  loadQ(0, qc, lc);

#pragma unroll
  for (int p = 0; p < 16; ++p) {
    const int buf = p & 1;
    __syncthreads();                     // drains head p's loads; buf^1 now free
    if (p < 15) stage(p + 1, buf ^ 1);   // prefetch overlaps head p's compute
    short8 qn[2][2]; floatx4 ln[2];
    loadQ(p < 15 ? p + 1 : 15, qn, ln);  // clamped; p==15 result unused
    const char* tb = (const char*)Ks[buf];
#pragma unroll
    for (int mi = 0; mi < 2; ++mi) {
      const int ib = i0 + wv * 32 + mi * 16;   // absolute 16-row subtile base
#pragma unroll
      for (int s = 0; s < 8; ++s) {
        const int jb = j0 + s * 16;
        if (jb > ib + 15) continue;            // fully masked (wave-uniform)
        const char* kr = tb + (s * 16 + lanem) * 128;
        short8 b0 = *(const short8*)(kr + (quad ^ swz) * 16);
        short8 b1 = *(const short8*)(kr + ((4 + quad) ^ swz) * 16);
        floatx4 sv = (floatx4){0.f, 0.f, 0.f, 0.f};
        sv = mfma16(qc[mi][0], b0, sv);
        sv = mfma16(qc[mi][1], b1, sv);
        if (jb + 15 <= ib) {                   // fully unmasked
#pragma unroll
          for (int r = 0; r < 4; ++r)
            acc[mi][s][r] += fexp2(sv[r]) * lc[mi][r];
        } else {                               // jb == ib: 16x16 diagonal
#pragma unroll
          for (int r = 0; r < 4; ++r)
            if (lanem <= quad * 4 + r)
              acc[mi][s][r] += fexp2(sv[r]) * lc[mi][r];
        }
      }
    }
#pragma unroll
    for (int mi = 0; mi < 2; ++mi) {
      qc[mi][0] = qn[mi][0]; qc[mi][1] = qn[mi][1]; lc[mi] = ln[mi];
    }
  }

#pragma unroll
  for (int mi = 0; mi < 2; ++mi)
#pragma unroll
    for (int s = 0; s < 8; ++s)
#pragma unroll
      for (int r = 0; r < 4; ++r) {
        int irow = i0 + wv * 32 + mi * 16 + quad * 4 + r;
        int jc = j0 + s * 16 + lanem;
        ob[(size_t)irow * L_ + jc] = acc[mi][s][r] * (1.0f / H_);
      }
}

// ---------------- host ----------------
extern "C" void kernel_launch(void* const* d_in, const int* in_sizes, int n_in,
                              void* d_out, int out_size, void* d_ws, size_t ws_size,
                              hipStream_t stream) {
  const float* query = (const float*)d_in[0];
  const float* key   = (const float*)d_in[1];
  const float* value = (const float*)d_in[2];
  const float* w_in  = (const float*)d_in[3];
  const float* b_in  = (const float*)d_in[4];
  const float* w_out = (const float*)d_in[5];
  const float* b_out = (const float*)d_in[6];

  char* ws = (char*)d_ws;
  size_t off = 0;
  auto alloc = [&](size_t bytes) -> void* {
    void* p = ws + off;
    off += (bytes + 255) & ~(size_t)255;
    return p;
  };
  u16* w_in_b  = (u16*)alloc((size_t)3 * E_ * K_ * 2);
  u16* w_out_b = (u16*)alloc((size_t)E_ * K_ * 2);
  u16* x_b     = (u16*)alloc((size_t)3 * M_ * K_ * 2);
  u16* qh      = (u16*)alloc((size_t)B_ * H_ * L_ * HD_ * 2);
  u16* kh      = (u16*)alloc((size_t)B_ * H_ * L_ * HD_ * 2);
  u16* vhT     = (u16*)alloc((size_t)B_ * H_ * L_ * HD_ * 2);
  u16* ctx     = (u16*)alloc((size_t)M_ * E_ * 2);
  float* li_ws = (float*)alloc((size_t)B_ * H_ * L_ * 4);

  // fp32 -> bf16, single launch for all 5 tensors
  convall<<<dim3(4096, 1, 5), 256, 0, stream>>>(
      query, key, value, w_in, w_out, x_b, w_in_b, w_out_b);

  // QKV projection (q output pre-scaled by QSCALE)
  gemm128<0><<<dim3(E_ / 128, M_ / 128, 3), 256, 0, stream>>>(
      x_b, w_in_b, b_in, qh, kh, vhT, nullptr);

  // flash attention -> ctx, 1/l (folded-triangle uniform blocks)
  attn1<<<dim3(L_ / 128, H_, B_), 256, 0, stream>>>(qh, kh, vhT, ctx, li_ws);

  // head-averaged probs -> second output (128x128 tiles)
  attn2<<<dim3(L_ / 128, L_ / 128, B_), 256, 0, stream>>>(
      qh, kh, li_ws, (float*)d_out + (size_t)M_ * E_);

  // out projection -> first output
  gemm128<1><<<dim3(E_ / 128, M_ / 128, 1), 256, 0, stream>>>(
      ctx, w_out_b, b_out, nullptr, nullptr, nullptr, (float*)d_out);
}